// Round 1
// baseline (416.193 us; speedup 1.0000x reference)
//
#include <hip/hip_runtime.h>
#include <hip/hip_bf16.h>
#include <stdint.h>

#define B_ 2
#define N_ 9
#define CB_ 80
#define H_ 120
#define W_ 160
#define D_ 64
#define P_ 80000
#define HW_ (H_*W_)        // 19200
#define NPIX_ (B_*N_*HW_)  // 345600
#define NEG_ (-10000.0f)

static __device__ __forceinline__ float bflo(uint32_t u) {
    return __uint_as_float(u << 16);
}
static __device__ __forceinline__ float bfhi(uint32_t u) {
    return __uint_as_float(u & 0xffff0000u);
}
// RNE float->bf16 bits
static __device__ __forceinline__ uint32_t f2bf_bits(float f) {
    uint32_t u = __float_as_uint(f);
    return (u + 0x7fffu + ((u >> 16) & 1u)) >> 16;
}

// ---------------------------------------------------------------------------
// Kernel 1: key_maps for BOTH blocks, fused.
//   km[pix][d][set] bf16, pix = ((b*9+n)*120+h)*160+w
// GEMM: [345600 x 80] x [80 x 128], tiled 64 pixels x 128 outputs per block.
// ---------------------------------------------------------------------------
__global__ __launch_bounds__(256) void keymap_kernel(
    const float* __restrict__ img,
    const float* __restrict__ Wk1, const float* __restrict__ bk1,
    const float* __restrict__ Wk2, const float* __restrict__ bk2,
    uint32_t* __restrict__ km)   // NPIX_*64 dwords (bf16 pairs)
{
    __shared__ __align__(16) float    a_lds[CB_ * 64];
    __shared__ __align__(16) uint16_t wk_lds[CB_ * 128];
    __shared__ float bias_lds[128];
    const int tid = threadIdx.x;

    // stage interleaved weights (bf16): wk_lds[c][j], j=2d+s
    for (int idx = tid; idx < CB_ * 128; idx += 256) {
        int c = idx >> 7, j = idx & 127;
        int d = j >> 1, s = j & 1;
        float v = s ? Wk2[d * CB_ + c] : Wk1[d * CB_ + c];
        wk_lds[idx] = (uint16_t)f2bf_bits(v);
    }
    if (tid < 128) {
        int d = tid >> 1, s = tid & 1;
        bias_lds[tid] = s ? bk2[d] : bk1[d];
    }

    const int pix0 = blockIdx.x * 64;
    const int bn   = pix0 / HW_;
    const int hw0  = pix0 - bn * HW_;
    const float* ibase = img + (size_t)bn * CB_ * HW_ + hw0;
    for (int idx = tid; idx < CB_ * 64; idx += 256) {
        int c = idx >> 6, px = idx & 63;
        a_lds[idx] = ibase[c * HW_ + px];
    }
    __syncthreads();

    const int dg = tid & 31;   // output group: j = dg*4 .. dg*4+3
    const int pg = tid >> 5;   // pixel group: pix0 + pg*8 .. +7
    float acc[8][4];
    {
        float b0 = bias_lds[dg * 4 + 0], b1 = bias_lds[dg * 4 + 1];
        float b2 = bias_lds[dg * 4 + 2], b3 = bias_lds[dg * 4 + 3];
        #pragma unroll
        for (int i = 0; i < 8; i++) {
            acc[i][0] = b0; acc[i][1] = b1; acc[i][2] = b2; acc[i][3] = b3;
        }
    }
    #pragma unroll 4
    for (int c = 0; c < CB_; c++) {
        float4 a0 = *reinterpret_cast<const float4*>(&a_lds[c * 64 + pg * 8]);
        float4 a1 = *reinterpret_cast<const float4*>(&a_lds[c * 64 + pg * 8 + 4]);
        uint2  wv = *reinterpret_cast<const uint2*>(&wk_lds[c * 128 + dg * 4]);
        float w0 = bflo(wv.x), w1 = bfhi(wv.x);
        float w2 = bflo(wv.y), w3 = bfhi(wv.y);
        float av[8] = {a0.x, a0.y, a0.z, a0.w, a1.x, a1.y, a1.z, a1.w};
        #pragma unroll
        for (int i = 0; i < 8; i++) {
            acc[i][0] += av[i] * w0;
            acc[i][1] += av[i] * w1;
            acc[i][2] += av[i] * w2;
            acc[i][3] += av[i] * w3;
        }
    }
    uint2* km2 = reinterpret_cast<uint2*>(km);
    #pragma unroll
    for (int i = 0; i < 8; i++) {
        int pix = pix0 + pg * 8 + i;
        uint2 o;
        o.x = f2bf_bits(acc[i][0]) | (f2bf_bits(acc[i][1]) << 16);
        o.y = f2bf_bits(acc[i][2]) | (f2bf_bits(acc[i][3]) << 16);
        km2[(size_t)pix * 32 + dg] = o;
    }
}

// ---------------------------------------------------------------------------
// Kernel 2: full per-point pipeline, both attention blocks fused.
// One wave per point, lane = feature dim d.
// ---------------------------------------------------------------------------
__global__ __launch_bounds__(256) void attn_kernel(
    const uint32_t* __restrict__ km,
    const int*   __restrict__ coords,
    const float* __restrict__ vfeat,
    const float* __restrict__ proj,
    const float* __restrict__ origins,
    const int*   __restrict__ cmask,
    const float* __restrict__ Wq1, const float* __restrict__ bq1,
    const float* __restrict__ Wq2, const float* __restrict__ bq2,
    float* __restrict__ out)
{
    // Wq rows padded to stride 66: lane d reads row d as float2 -> banks (2d+c)%32,
    // 2-way conflict (free). f_lds reads are wave-uniform broadcasts.
    __shared__ __align__(16) float wq_lds[2 * 64 * 66];
    __shared__ __align__(16) float f_lds[4 * 64];
    __shared__ float bq_lds[128];
    const int tid = threadIdx.x;

    for (int idx = tid; idx < 4096; idx += 256) {
        int d = idx >> 6, c = idx & 63;
        wq_lds[d * 66 + c]           = Wq1[idx];
        wq_lds[64 * 66 + d * 66 + c] = Wq2[idx];
    }
    if (tid < 128) bq_lds[tid] = (tid < 64) ? bq1[tid] : bq2[tid - 64];
    __syncthreads();

    const int lane = tid & 63;
    const int wid  = tid >> 6;
    const int p    = blockIdx.x * 4 + wid;

    const int bi = coords[p * 4 + 3];
    const float wldx = (float)coords[p * 4 + 0] * 0.16f + origins[bi * 3 + 0];
    const float wldy = (float)coords[p * 4 + 1] * 0.16f + origins[bi * 3 + 1];
    const float wldz = (float)coords[p * 4 + 2] * 0.16f + origins[bi * 3 + 2];
    const bool  sel  = cmask[p] > 1;

    // lanes 0..8: projection for view n = lane
    int packw = -1; float fx = 0.f, fy = 0.f;
    if (lane < N_) {
        const float* Pr = proj + (size_t)(bi * N_ + lane) * 12;
        float c0 = Pr[0]*wldx + Pr[1]*wldy + Pr[2]*wldz  + Pr[3];
        float c1 = Pr[4]*wldx + Pr[5]*wldy + Pr[6]*wldz  + Pr[7];
        float c2 = Pr[8]*wldx + Pr[9]*wldy + Pr[10]*wldz + Pr[11];
        float gx = 2.f * (c0 / c2) / (float)(W_ - 1) - 1.f;
        float gy = 2.f * (c1 / c2) / (float)(H_ - 1) - 1.f;
        if (fabsf(gx) <= 1.f && fabsf(gy) <= 1.f && c2 > 0.f) {
            float px = (gx + 1.f) * 0.5f * (float)(W_ - 1);
            float py = (gy + 1.f) * 0.5f * (float)(H_ - 1);
            float x0 = floorf(px), y0 = floorf(py);
            fx = px - x0; fy = py - y0;
            int x0i = (int)x0, y0i = (int)y0;
            int pb = ((bi * N_ + lane) * H_ + y0i) * W_ + x0i;
            packw = pb | ((x0i < W_ - 1) ? (1 << 20) : 0)
                       | ((y0i < H_ - 1) ? (1 << 21) : 0);
        }
    }

    const float vf = vfeat[(size_t)p * 64 + lane];

    // broadcast per-view params
    int   pwv[N_];
    float kf1[N_], kf2[N_];
    #pragma unroll
    for (int n = 0; n < N_; n++) pwv[n] = __shfl(packw, n);

    // bilinear-sample both key maps (one dword per tap per lane)
    #pragma unroll
    for (int n = 0; n < N_; n++) {
        kf1[n] = 0.f; kf2[n] = 0.f;
        int pw = pwv[n];
        if (pw >= 0) {
            float wx = __shfl(fx, n), wy = __shfl(fy, n);
            int pb  = pw & 0xFFFFF;
            int dxo = (pw & (1 << 20)) ? 64 : 0;
            int dyo = (pw & (1 << 21)) ? (W_ * 64) : 0;
            const uint32_t* kb = km + (size_t)pb * 64 + lane;
            uint32_t u00 = kb[0];
            uint32_t u01 = kb[dxo];
            uint32_t u10 = kb[dyo];
            uint32_t u11 = kb[dyo + dxo];
            float w11 = wx * wy;
            float w01 = wx - w11;
            float w10 = wy - w11;
            float w00 = 1.f - wx - wy + w11;
            kf1[n] = w00*bflo(u00) + w01*bflo(u01) + w10*bflo(u10) + w11*bflo(u11);
            kf2[n] = w00*bfhi(u00) + w01*bfhi(u01) + w10*bfhi(u10) + w11*bfhi(u11);
        }
    }

    // ---- block 1 ----
    f_lds[wid * 64 + lane] = vf;
    __syncthreads();
    float q1 = bq_lds[lane];
    {
        const float2* wrow = reinterpret_cast<const float2*>(&wq_lds[lane * 66]);
        const float2* fv   = reinterpret_cast<const float2*>(&f_lds[wid * 64]);
        #pragma unroll 8
        for (int cc = 0; cc < 32; cc++) {
            float2 w = wrow[cc]; float2 v = fv[cc];
            q1 += w.x * v.x + w.y * v.y;
        }
    }

    float l1[N_];
    #pragma unroll
    for (int n = 0; n < N_; n++) {
        float t = q1 * kf1[n];
        #pragma unroll
        for (int off = 32; off >= 1; off >>= 1) t += __shfl_xor(t, off);
        l1[n] = (pwv[n] >= 0) ? t * 0.125f : NEG_;
    }
    float mx = l1[0];
    #pragma unroll
    for (int n = 1; n < N_; n++) mx = fmaxf(mx, l1[n]);
    float ssum = 0.f, pr[N_];
    #pragma unroll
    for (int n = 0; n < N_; n++) { pr[n] = __expf(l1[n] - mx); ssum += pr[n]; }
    float inv = 1.f / ssum;
    float y1 = 0.f;
    #pragma unroll
    for (int n = 0; n < N_; n++) y1 += pr[n] * kf1[n];
    y1 *= inv;
    const float fcur = vf + (sel ? y1 : 0.f);

    // ---- block 2 ----
    __syncthreads();
    f_lds[wid * 64 + lane] = fcur;
    __syncthreads();
    float q2 = bq_lds[64 + lane];
    {
        const float2* wrow = reinterpret_cast<const float2*>(&wq_lds[64 * 66 + lane * 66]);
        const float2* fv   = reinterpret_cast<const float2*>(&f_lds[wid * 64]);
        #pragma unroll 8
        for (int cc = 0; cc < 32; cc++) {
            float2 w = wrow[cc]; float2 v = fv[cc];
            q2 += w.x * v.x + w.y * v.y;
        }
    }

    float l2[N_];
    #pragma unroll
    for (int n = 0; n < N_; n++) {
        float t = q2 * kf2[n];
        #pragma unroll
        for (int off = 32; off >= 1; off >>= 1) t += __shfl_xor(t, off);
        l2[n] = (pwv[n] >= 0) ? t * 0.125f : NEG_;
    }
    float mx2 = l2[0];
    #pragma unroll
    for (int n = 1; n < N_; n++) mx2 = fmaxf(mx2, l2[n]);
    float ssum2 = 0.f, pr2[N_];
    #pragma unroll
    for (int n = 0; n < N_; n++) { pr2[n] = __expf(l2[n] - mx2); ssum2 += pr2[n]; }
    float inv2 = 1.f / ssum2;
    float y2 = 0.f;
    #pragma unroll
    for (int n = 0; n < N_; n++) y2 += pr2[n] * kf2[n];
    y2 *= inv2;

    out[(size_t)p * 64 + lane] = fcur + (sel ? y2 : 0.f);
}

extern "C" void kernel_launch(void* const* d_in, const int* in_sizes, int n_in,
                              void* d_out, int out_size, void* d_ws, size_t ws_size,
                              hipStream_t stream) {
    const float* img    = (const float*)d_in[0];
    const int*   coords = (const int*)  d_in[1];
    const float* vf     = (const float*)d_in[2];
    const float* proj   = (const float*)d_in[3];
    const float* org    = (const float*)d_in[4];
    const int*   cm     = (const int*)  d_in[5];
    const float* Wq1    = (const float*)d_in[6];
    const float* bq1    = (const float*)d_in[7];
    const float* Wk1    = (const float*)d_in[8];
    const float* bk1    = (const float*)d_in[9];
    const float* Wq2    = (const float*)d_in[10];
    const float* bq2    = (const float*)d_in[11];
    const float* Wk2    = (const float*)d_in[12];
    const float* bk2    = (const float*)d_in[13];

    uint32_t* km = (uint32_t*)d_ws;   // NPIX_*64 dwords = 88.5 MB
    float*    o  = (float*)d_out;

    keymap_kernel<<<dim3(NPIX_ / 64), dim3(256), 0, stream>>>(img, Wk1, bk1, Wk2, bk2, km);
    attn_kernel<<<dim3(P_ / 4), dim3(256), 0, stream>>>(km, coords, vf, proj, org, cm,
                                                        Wq1, bq1, Wq2, bq2, o);
}

// Round 2
// 327.637 us; speedup vs baseline: 1.2703x; 1.2703x over previous
//
#include <hip/hip_runtime.h>
#include <hip/hip_bf16.h>
#include <stdint.h>

#define B_ 2
#define N_ 9
#define CB_ 80
#define H_ 120
#define W_ 160
#define D_ 64
#define P_ 80000
#define HW_ (H_*W_)        // 19200
#define NPIX_ (B_*N_*HW_)  // 345600
#define NEG_ (-10000.0f)

static __device__ __forceinline__ float bflo(uint32_t u) {
    return __uint_as_float(u << 16);
}
static __device__ __forceinline__ float bfhi(uint32_t u) {
    return __uint_as_float(u & 0xffff0000u);
}
// RNE float->bf16 bits
static __device__ __forceinline__ uint32_t f2bf_bits(float f) {
    uint32_t u = __float_as_uint(f);
    return (u + 0x7fffu + ((u >> 16) & 1u)) >> 16;
}

// ---------------------------------------------------------------------------
// Kernel 1: key_maps for BOTH blocks, fused.  (unchanged this round)
//   km[pix][d][set] bf16, pix = ((b*9+n)*120+h)*160+w
// ---------------------------------------------------------------------------
__global__ __launch_bounds__(256) void keymap_kernel(
    const float* __restrict__ img,
    const float* __restrict__ Wk1, const float* __restrict__ bk1,
    const float* __restrict__ Wk2, const float* __restrict__ bk2,
    uint32_t* __restrict__ km)   // NPIX_*64 dwords (bf16 pairs)
{
    __shared__ __align__(16) float    a_lds[CB_ * 64];
    __shared__ __align__(16) uint16_t wk_lds[CB_ * 128];
    __shared__ float bias_lds[128];
    const int tid = threadIdx.x;

    for (int idx = tid; idx < CB_ * 128; idx += 256) {
        int c = idx >> 7, j = idx & 127;
        int d = j >> 1, s = j & 1;
        float v = s ? Wk2[d * CB_ + c] : Wk1[d * CB_ + c];
        wk_lds[idx] = (uint16_t)f2bf_bits(v);
    }
    if (tid < 128) {
        int d = tid >> 1, s = tid & 1;
        bias_lds[tid] = s ? bk2[d] : bk1[d];
    }

    const int pix0 = blockIdx.x * 64;
    const int bn   = pix0 / HW_;
    const int hw0  = pix0 - bn * HW_;
    const float* ibase = img + (size_t)bn * CB_ * HW_ + hw0;
    for (int idx = tid; idx < CB_ * 64; idx += 256) {
        int c = idx >> 6, px = idx & 63;
        a_lds[idx] = ibase[c * HW_ + px];
    }
    __syncthreads();

    const int dg = tid & 31;
    const int pg = tid >> 5;
    float acc[8][4];
    {
        float b0 = bias_lds[dg * 4 + 0], b1 = bias_lds[dg * 4 + 1];
        float b2 = bias_lds[dg * 4 + 2], b3 = bias_lds[dg * 4 + 3];
        #pragma unroll
        for (int i = 0; i < 8; i++) {
            acc[i][0] = b0; acc[i][1] = b1; acc[i][2] = b2; acc[i][3] = b3;
        }
    }
    #pragma unroll 4
    for (int c = 0; c < CB_; c++) {
        float4 a0 = *reinterpret_cast<const float4*>(&a_lds[c * 64 + pg * 8]);
        float4 a1 = *reinterpret_cast<const float4*>(&a_lds[c * 64 + pg * 8 + 4]);
        uint2  wv = *reinterpret_cast<const uint2*>(&wk_lds[c * 128 + dg * 4]);
        float w0 = bflo(wv.x), w1 = bfhi(wv.x);
        float w2 = bflo(wv.y), w3 = bfhi(wv.y);
        float av[8] = {a0.x, a0.y, a0.z, a0.w, a1.x, a1.y, a1.z, a1.w};
        #pragma unroll
        for (int i = 0; i < 8; i++) {
            acc[i][0] += av[i] * w0;
            acc[i][1] += av[i] * w1;
            acc[i][2] += av[i] * w2;
            acc[i][3] += av[i] * w3;
        }
    }
    uint2* km2 = reinterpret_cast<uint2*>(km);
    #pragma unroll
    for (int i = 0; i < 8; i++) {
        int pix = pix0 + pg * 8 + i;
        uint2 o;
        o.x = f2bf_bits(acc[i][0]) | (f2bf_bits(acc[i][1]) << 16);
        o.y = f2bf_bits(acc[i][2]) | (f2bf_bits(acc[i][3]) << 16);
        km2[(size_t)pix * 32 + dg] = o;
    }
}

// ---------------------------------------------------------------------------
// Kernel 2: persistent-wave attention. Grid = 1024 blocks (4/CU resident),
// each wave loops over ~20 points. Wq staged ONCE per block; no per-point
// barriers (per-wave f_lds slot, within-wave LDS ordering suffices).
// ---------------------------------------------------------------------------
__global__ __launch_bounds__(256) void attn_kernel(
    const uint32_t* __restrict__ km,
    const int*   __restrict__ coords,
    const float* __restrict__ vfeat,
    const float* __restrict__ proj,
    const float* __restrict__ origins,
    const int*   __restrict__ cmask,
    const float* __restrict__ Wq1, const float* __restrict__ bq1,
    const float* __restrict__ Wq2, const float* __restrict__ bq2,
    float* __restrict__ out)
{
    __shared__ __align__(16) float wq_lds[2 * 64 * 66];
    __shared__ __align__(16) float f_lds[4 * 64];
    __shared__ float bq_lds[128];
    __shared__ float proj_lds[B_ * N_ * 12];   // 216
    const int tid = threadIdx.x;

    for (int idx = tid; idx < 4096; idx += 256) {
        int d = idx >> 6, c = idx & 63;
        wq_lds[d * 66 + c]           = Wq1[idx];
        wq_lds[64 * 66 + d * 66 + c] = Wq2[idx];
    }
    if (tid < 128) bq_lds[tid] = (tid < 64) ? bq1[tid] : bq2[tid - 64];
    if (tid < B_ * N_ * 12) proj_lds[tid] = proj[tid];
    __syncthreads();

    const int lane = tid & 63;
    const int wid  = tid >> 6;
    const int nw   = gridDim.x * 4;

    // origins in registers (B=2)
    const float o0x = origins[0], o0y = origins[1], o0z = origins[2];
    const float o1x = origins[3], o1y = origins[4], o1z = origins[5];

    const int4* coords4 = reinterpret_cast<const int4*>(coords);

    int p = blockIdx.x * 4 + wid;
    int4  cv  = coords4[p];
    float vf  = vfeat[(size_t)p * 64 + lane];
    int   cmv = cmask[p];

    while (true) {
        // ---- prefetch next point's scalars ----
        const int pn = p + nw;
        const bool have_next = pn < P_;
        int4 cv_n; float vf_n = 0.f; int cm_n = 0;
        if (have_next) {
            cv_n = coords4[pn];
            vf_n = vfeat[(size_t)pn * 64 + lane];
            cm_n = cmask[pn];
        }

        // ---- projection (lanes 0..8) ----
        const int  bi   = cv.w;
        const float wldx = (float)cv.x * 0.16f + (bi ? o1x : o0x);
        const float wldy = (float)cv.y * 0.16f + (bi ? o1y : o0y);
        const float wldz = (float)cv.z * 0.16f + (bi ? o1z : o0z);
        const bool sel = cmv > 1;

        int packw = -1; float fx = 0.f, fy = 0.f;
        if (lane < N_) {
            const float* Pr = &proj_lds[(bi * N_ + lane) * 12];
            float c0 = Pr[0]*wldx + Pr[1]*wldy + Pr[2]*wldz  + Pr[3];
            float c1 = Pr[4]*wldx + Pr[5]*wldy + Pr[6]*wldz  + Pr[7];
            float c2 = Pr[8]*wldx + Pr[9]*wldy + Pr[10]*wldz + Pr[11];
            float gx = 2.f * (c0 / c2) / (float)(W_ - 1) - 1.f;
            float gy = 2.f * (c1 / c2) / (float)(H_ - 1) - 1.f;
            if (fabsf(gx) <= 1.f && fabsf(gy) <= 1.f && c2 > 0.f) {
                float px = (gx + 1.f) * 0.5f * (float)(W_ - 1);
                float py = (gy + 1.f) * 0.5f * (float)(H_ - 1);
                float x0 = floorf(px), y0 = floorf(py);
                fx = px - x0; fy = py - y0;
                int x0i = (int)x0, y0i = (int)y0;
                int pb = ((bi * N_ + lane) * H_ + y0i) * W_ + x0i;
                packw = pb | ((x0i < W_ - 1) ? (1 << 20) : 0)
                           | ((y0i < H_ - 1) ? (1 << 21) : 0);
            }
        }

        int   pwv[N_];
        float kf1[N_], kf2[N_];
        #pragma unroll
        for (int n = 0; n < N_; n++) pwv[n] = __shfl(packw, n);

        // ---- bilinear sample both key maps ----
        #pragma unroll
        for (int n = 0; n < N_; n++) {
            kf1[n] = 0.f; kf2[n] = 0.f;
            int pw = pwv[n];
            if (pw >= 0) {
                float wx = __shfl(fx, n), wy = __shfl(fy, n);
                int pb  = pw & 0xFFFFF;
                int dxo = (pw & (1 << 20)) ? 64 : 0;
                int dyo = (pw & (1 << 21)) ? (W_ * 64) : 0;
                const uint32_t* kb = km + (size_t)pb * 64 + lane;
                uint32_t u00 = kb[0];
                uint32_t u01 = kb[dxo];
                uint32_t u10 = kb[dyo];
                uint32_t u11 = kb[dyo + dxo];
                float w11 = wx * wy;
                float w01 = wx - w11;
                float w10 = wy - w11;
                float w00 = 1.f - wx - wy + w11;
                kf1[n] = w00*bflo(u00) + w01*bflo(u01) + w10*bflo(u10) + w11*bflo(u11);
                kf2[n] = w00*bfhi(u00) + w01*bfhi(u01) + w10*bfhi(u10) + w11*bfhi(u11);
            }
        }

        // ---- block 1: q = Wq1 f + bq1 ----
        f_lds[wid * 64 + lane] = vf;
        float q1 = bq_lds[lane];
        {
            const float2* wrow = reinterpret_cast<const float2*>(&wq_lds[lane * 66]);
            const float2* fv   = reinterpret_cast<const float2*>(&f_lds[wid * 64]);
            #pragma unroll 8
            for (int cc = 0; cc < 32; cc++) {
                float2 w = wrow[cc]; float2 v = fv[cc];
                q1 += w.x * v.x + w.y * v.y;
            }
        }
        q1 *= 0.125f;  // fold 1/sqrt(D), exact pow2

        float l1[N_];
        #pragma unroll
        for (int n = 0; n < N_; n++) {
            float t = q1 * kf1[n];
            #pragma unroll
            for (int off = 32; off >= 1; off >>= 1) t += __shfl_xor(t, off);
            l1[n] = (pwv[n] >= 0) ? t : NEG_;
        }
        float mx = l1[0];
        #pragma unroll
        for (int n = 1; n < N_; n++) mx = fmaxf(mx, l1[n]);
        float ssum = 0.f, pr[N_];
        #pragma unroll
        for (int n = 0; n < N_; n++) { pr[n] = __expf(l1[n] - mx); ssum += pr[n]; }
        float inv = 1.f / ssum;
        float y1 = 0.f;
        #pragma unroll
        for (int n = 0; n < N_; n++) y1 += pr[n] * kf1[n];
        y1 *= inv;
        const float fcur = vf + (sel ? y1 : 0.f);

        // ---- block 2 ----
        f_lds[wid * 64 + lane] = fcur;
        float q2 = bq_lds[64 + lane];
        {
            const float2* wrow = reinterpret_cast<const float2*>(&wq_lds[64 * 66 + lane * 66]);
            const float2* fv   = reinterpret_cast<const float2*>(&f_lds[wid * 64]);
            #pragma unroll 8
            for (int cc = 0; cc < 32; cc++) {
                float2 w = wrow[cc]; float2 v = fv[cc];
                q2 += w.x * v.x + w.y * v.y;
            }
        }
        q2 *= 0.125f;

        float l2[N_];
        #pragma unroll
        for (int n = 0; n < N_; n++) {
            float t = q2 * kf2[n];
            #pragma unroll
            for (int off = 32; off >= 1; off >>= 1) t += __shfl_xor(t, off);
            l2[n] = (pwv[n] >= 0) ? t : NEG_;
        }
        float mx2 = l2[0];
        #pragma unroll
        for (int n = 1; n < N_; n++) mx2 = fmaxf(mx2, l2[n]);
        float ssum2 = 0.f, pr2[N_];
        #pragma unroll
        for (int n = 0; n < N_; n++) { pr2[n] = __expf(l2[n] - mx2); ssum2 += pr2[n]; }
        float inv2 = 1.f / ssum2;
        float y2 = 0.f;
        #pragma unroll
        for (int n = 0; n < N_; n++) y2 += pr2[n] * kf2[n];
        y2 *= inv2;

        out[(size_t)p * 64 + lane] = fcur + (sel ? y2 : 0.f);

        if (!have_next) break;
        p = pn; cv = cv_n; vf = vf_n; cmv = cm_n;
    }
}

extern "C" void kernel_launch(void* const* d_in, const int* in_sizes, int n_in,
                              void* d_out, int out_size, void* d_ws, size_t ws_size,
                              hipStream_t stream) {
    const float* img    = (const float*)d_in[0];
    const int*   coords = (const int*)  d_in[1];
    const float* vf     = (const float*)d_in[2];
    const float* proj   = (const float*)d_in[3];
    const float* org    = (const float*)d_in[4];
    const int*   cm     = (const int*)  d_in[5];
    const float* Wq1    = (const float*)d_in[6];
    const float* bq1    = (const float*)d_in[7];
    const float* Wk1    = (const float*)d_in[8];
    const float* bk1    = (const float*)d_in[9];
    const float* Wq2    = (const float*)d_in[10];
    const float* bq2    = (const float*)d_in[11];
    const float* Wk2    = (const float*)d_in[12];
    const float* bk2    = (const float*)d_in[13];

    uint32_t* km = (uint32_t*)d_ws;   // NPIX_*64 dwords = 88.5 MB
    float*    o  = (float*)d_out;

    keymap_kernel<<<dim3(NPIX_ / 64), dim3(256), 0, stream>>>(img, Wk1, bk1, Wk2, bk2, km);
    attn_kernel<<<dim3(1024), dim3(256), 0, stream>>>(km, coords, vf, proj, org, cm,
                                                      Wq1, bq1, Wq2, bq2, o);
}